// Round 6
// baseline (345.667 us; speedup 1.0000x reference)
//
#include <hip/hip_runtime.h>
#include <stdint.h>

#define Bq 8
#define Mq 1024
#define Hq 512
#define NHq 8
#define Dq 64
#define SPANq 1024
#define MKq 2048
#define PR2 168   // attn P-row stride (ushorts); 160 used

typedef __bf16 bf16x8 __attribute__((ext_vector_type(8)));
typedef _Float16 f16x8 __attribute__((ext_vector_type(8)));
typedef float f32x4 __attribute__((ext_vector_type(4)));
typedef unsigned short ushort8 __attribute__((ext_vector_type(8)));
typedef unsigned int uint2v __attribute__((ext_vector_type(2)));
typedef unsigned int uint4v __attribute__((ext_vector_type(4)));

static __device__ __forceinline__ unsigned short f2bf(float f) {
  union { float f; unsigned u; } x; x.f = f;
  unsigned r = x.u + 0x7FFFu + ((x.u >> 16) & 1u);
  return (unsigned short)(r >> 16);
}

static __device__ __forceinline__ unsigned pk_f16(float a, float b) {
  return __builtin_bit_cast(unsigned, __builtin_amdgcn_cvt_pkrtz(a, b));
}

// packed f32x2 -> bf16x2 (RNE), gfx940+ instruction (no builtin; see learn_hip m240)
static __device__ __forceinline__ unsigned pk_bf16(float a, float b) {
  unsigned r;
  asm("v_cvt_pk_bf16_f32 %0, %1, %2" : "=v"(r) : "v"(a), "v"(b));
  return r;
}

static __device__ __forceinline__ f32x4 mfma_bf16(bf16x8 a, bf16x8 b, f32x4 c) {
  return __builtin_amdgcn_mfma_f32_16x16x32_bf16(a, b, c, 0, 0, 0);
}
static __device__ __forceinline__ f32x4 mfma_f16(f16x8 a, f16x8 b, f32x4 c) {
  return __builtin_amdgcn_mfma_f32_16x16x32_f16(a, b, c, 0, 0, 0);
}

// async 16B/lane global->LDS DMA; lds dest = uniform base + lane*16
static __device__ __forceinline__ void async_ld16(const void* g, void* l) {
  __builtin_amdgcn_global_load_lds(
      (const __attribute__((address_space(1))) void*)g,
      (__attribute__((address_space(3))) void*)l, 16, 0, 0);
}

// ---------------- prep: transpose+convert weights (WT[o][i]=W[i][o]) and pos (posT[s][d]=pos[d][s])
__global__ __launch_bounds__(256) void prep_transpose(
    const float* __restrict__ Wq, const float* __restrict__ Wk,
    const float* __restrict__ Wv, const float* __restrict__ Wo,
    const float* __restrict__ pos,
    unsigned short* __restrict__ WTq, unsigned short* __restrict__ WTk,
    unsigned short* __restrict__ WTv, unsigned short* __restrict__ WTo,
    unsigned short* __restrict__ posT) {
  __shared__ float tile[64][65];
  const int bid = blockIdx.x;
  const float* src; unsigned short* dst;
  int src_stride, dst_stride, i0, o0;
  if (bid < 256) {
    const int w = bid >> 6, t = bid & 63;
    src = (w == 0) ? Wq : (w == 1) ? Wk : (w == 2) ? Wv : Wo;
    dst = (w == 0) ? WTq : (w == 1) ? WTk : (w == 2) ? WTv : WTo;
    src_stride = Hq; dst_stride = Hq;
    i0 = (t >> 3) * 64; o0 = (t & 7) * 64;
  } else {
    const int t = bid - 256;
    src = pos; dst = posT;
    src_stride = SPANq; dst_stride = Dq;
    i0 = 0; o0 = t * 64;
  }
  const int tid = threadIdx.x;
  for (int e = tid; e < 4096; e += 256) {
    const int r = e >> 6, c = e & 63;
    tile[r][c] = src[(size_t)(i0 + r) * src_stride + o0 + c];
  }
  __syncthreads();
  for (int e = tid; e < 4096; e += 256) {
    const int r = e >> 6, c = e & 63;
    dst[(size_t)(o0 + r) * dst_stride + i0 + c] = f2bf(tile[c][r]);
  }
}

// ---------------- 128x128 GEMM via global_load_lds staging (BK=64, XOR-swizzled)
// bf16 A input (used for out-projection, mode 3: fp32 row-major output)
__global__ __launch_bounds__(256, 2) void gemm128(
    const unsigned short* __restrict__ Xb, const unsigned short* __restrict__ WT,
    unsigned short* __restrict__ outb, _Float16* __restrict__ outv,
    float* __restrict__ outf, int mode, int tshift) {
  __shared__ unsigned short sh[18432];   // 36 KB
  unsigned short* As = sh;               // [128][64] unpadded, swizzled
  unsigned short* Bs = sh + 8192;
  const int tid = threadIdx.x;
  const int wave = tid >> 6, lane = tid & 63;
  const int q = lane >> 4, l16 = lane & 15;
  const int wy = wave >> 1, wx = wave & 1;
  const size_t m0 = (size_t)blockIdx.x * 128;
  const int n0 = blockIdx.y * 128;
  const int dsub = lane >> 3;                 // row offset within slot
  const int dswz = (lane & 7) ^ dsub;         // swizzled source chunk

  f32x4 acc[4][4] = {};

  for (int k0 = 0; k0 < Hq; k0 += 64) {
    __syncthreads();
#pragma unroll
    for (int i = 0; i < 4; i++) {
      const int s = wave * 4 + i;             // slot 0..15, 8 rows each
      const int r = s * 8 + dsub;             // row 0..127
      async_ld16(Xb + (m0 + r) * Hq + k0 + dswz * 8, As + s * 512);
      async_ld16(WT + (size_t)(n0 + r) * Hq + k0 + dswz * 8, Bs + s * 512);
    }
    __syncthreads();
    bf16x8 af[2][4], bg[2][4];
#pragma unroll
    for (int h = 0; h < 2; h++) {
#pragma unroll
      for (int mt = 0; mt < 4; mt++) {
        const int R = wy * 64 + mt * 16 + l16;
        af[h][mt] = *(const bf16x8*)(As + R * 64 + (((h * 4 + q) ^ (l16 & 7)) * 8));
      }
#pragma unroll
      for (int nt = 0; nt < 4; nt++) {
        const int R = wx * 64 + nt * 16 + l16;
        bg[h][nt] = *(const bf16x8*)(Bs + R * 64 + (((h * 4 + q) ^ (l16 & 7)) * 8));
      }
    }
#pragma unroll
    for (int h = 0; h < 2; h++)
#pragma unroll
      for (int mt = 0; mt < 4; mt++)
#pragma unroll
        for (int nt = 0; nt < 4; nt++)
          acc[mt][nt] = mfma_bf16(af[h][mt], bg[h][nt], acc[mt][nt]);
  }

  const int Tlen = 1 << tshift;
#pragma unroll
  for (int mt = 0; mt < 4; mt++) {
#pragma unroll
    for (int nt = 0; nt < 4; nt++) {
      const int c = n0 + wx * 64 + nt * 16 + l16;
#pragma unroll
      for (int r = 0; r < 4; r++) {
        const int m = (int)m0 + wy * 64 + mt * 16 + q * 4 + r;
        const float val = acc[mt][nt][r];
        if (mode == 3) {
          outf[(size_t)m * Hq + c] = val;
        } else {
          const int b = m >> tshift, t = m & (Tlen - 1);
          const int head = c >> 6, d = c & 63;
          outb[(((size_t)(b * 8 + head) << tshift) + t) * 64 + d] = f2bf(val);
        }
      }
    }
  }
}

// ---------------- fused Q/K/V projection: fp32 X staged directly (conv_bf16 eliminated)
// A tile staged as fp32 [128][64] (32 KB, 32 slots x 4 rows), swizzle on 4-float chunks:
// LDS[r][p] = src[r][p ^ (r&7)]. LDS->frag converts via v_cvt_pk_bf16_f32.
__global__ __launch_bounds__(256, 2) void gemm_qkv(
    const float* __restrict__ qF, const float* __restrict__ kF,
    const float* __restrict__ vF,
    const unsigned short* __restrict__ WTq, const unsigned short* __restrict__ WTk,
    const unsigned short* __restrict__ WTv,
    unsigned short* __restrict__ qb, unsigned short* __restrict__ kbuf,
    _Float16* __restrict__ vTb) {
  __shared__ float shf[12288];                 // 48 KB: As fp32 32 KB + Bs bf16 16 KB
  float* As = shf;                             // [128][64] fp32, swizzled
  unsigned short* Bs = (unsigned short*)(shf + 8192);

  const int x = blockIdx.x;
  const float* Xf; const unsigned short* WT;
  unsigned short* outb = nullptr; _Float16* outv = nullptr;
  int mode, tshift, bx;
  if (x < 64)       { Xf = qF; WT = WTq; outb = qb;   mode = 0; tshift = 10; bx = x; }
  else if (x < 192) { Xf = kF; WT = WTk; outb = kbuf; mode = 0; tshift = 11; bx = x - 64; }
  else              { Xf = vF; WT = WTv; outv = vTb;  mode = 2; tshift = 11; bx = x - 192; }

  const int tid = threadIdx.x;
  const int wave = tid >> 6, lane = tid & 63;
  const int q = lane >> 4, l16 = lane & 15;
  const int wy = wave >> 1, wx = wave & 1;
  const size_t m0 = (size_t)bx * 128;
  const int n0 = blockIdx.y * 128;
  const int dsub = lane >> 3;
  const int dswz = (lane & 7) ^ dsub;
  const int arow = lane >> 4;                  // 0..3 within A slot
  const int apos = lane & 15;                  // chunk position 0..15

  f32x4 acc[4][4] = {};

  for (int k0 = 0; k0 < Hq; k0 += 64) {
    __syncthreads();
#pragma unroll
    for (int i = 0; i < 8; i++) {
      const int s = wave * 8 + i;              // A slot 0..31, 4 rows each
      const int r = s * 4 + arow;              // row 0..127
      const int gsw = apos ^ (((s & 1) << 2) | arow);  // = apos ^ (r&7)
      async_ld16(Xf + (m0 + r) * Hq + k0 + gsw * 4, As + s * 256);
    }
#pragma unroll
    for (int i = 0; i < 4; i++) {
      const int s = wave * 4 + i;              // B slot 0..15, 8 rows each
      const int r = s * 8 + dsub;
      async_ld16(WT + (size_t)(n0 + r) * Hq + k0 + dswz * 8, Bs + s * 512);
    }
    __syncthreads();

    bf16x8 af[2][4], bg[2][4];
#pragma unroll
    for (int h = 0; h < 2; h++) {
#pragma unroll
      for (int mt = 0; mt < 4; mt++) {
        const int R = wy * 64 + mt * 16 + l16;
        const int xr = R & 7;
        const int c0 = h * 8 + q * 2;          // 4-float chunk index (k = c0*4)
        const f32x4 a0 = *(const f32x4*)(As + R * 64 + ((c0 ^ xr) * 4));
        const f32x4 a1 = *(const f32x4*)(As + R * 64 + (((c0 + 1) ^ xr) * 4));
        uint4v w;
        w[0] = pk_bf16(a0[0], a0[1]);
        w[1] = pk_bf16(a0[2], a0[3]);
        w[2] = pk_bf16(a1[0], a1[1]);
        w[3] = pk_bf16(a1[2], a1[3]);
        af[h][mt] = __builtin_bit_cast(bf16x8, w);
      }
#pragma unroll
      for (int nt = 0; nt < 4; nt++) {
        const int R = wx * 64 + nt * 16 + l16;
        bg[h][nt] = *(const bf16x8*)(Bs + R * 64 + (((h * 4 + q) ^ (l16 & 7)) * 8));
      }
    }
#pragma unroll
    for (int h = 0; h < 2; h++)
#pragma unroll
      for (int mt = 0; mt < 4; mt++)
#pragma unroll
        for (int nt = 0; nt < 4; nt++)
          acc[mt][nt] = mfma_bf16(af[h][mt], bg[h][nt], acc[mt][nt]);
  }

  if (mode == 2) {
    __syncthreads();  // protect tile LDS before reuse
    _Float16* tr = (_Float16*)shf + wave * 4608;  // [64][72]
#pragma unroll
    for (int nt = 0; nt < 4; nt++)
#pragma unroll
      for (int mt = 0; mt < 4; mt++)
#pragma unroll
        for (int r = 0; r < 4; r++)
          tr[(nt * 16 + l16) * 72 + mt * 16 + q * 4 + r] = (_Float16)acc[mt][nt][r];
    const int head = blockIdx.y * 2 + wx;
    const int mrow0 = (int)m0 + wy * 64;
    const int Tlen = 1 << tshift;
    const int b = mrow0 >> tshift, t0 = mrow0 & (Tlen - 1);
#pragma unroll
    for (int it = 0; it < 8; it++) {
      const int dl = it * 8 + (lane >> 3), tl = (lane & 7) * 8;
      const f16x8 v = *(const f16x8*)(tr + dl * 72 + tl);
      *(f16x8*)(outv + ((size_t)((b * 8 + head) * 64 + dl)) * Tlen + t0 + tl) = v;
    }
    return;
  }

  const int Tlen = 1 << tshift;
#pragma unroll
  for (int mt = 0; mt < 4; mt++) {
#pragma unroll
    for (int nt = 0; nt < 4; nt++) {
      const int c = n0 + wx * 64 + nt * 16 + l16;
#pragma unroll
      for (int r = 0; r < 4; r++) {
        const int m = (int)m0 + wy * 64 + mt * 16 + q * 4 + r;
        const int b = m >> tshift, t = m & (Tlen - 1);
        const int head = c >> 6, d = c & 63;
        outb[(((size_t)(b * 8 + head) << tshift) + t) * 64 + d] = f2bf(acc[mt][nt][r]);
      }
    }
  }
}

// ---------------- banded attention: K dbuf prefetch with FIFO-clean compute phase.
// vmcnt is an in-order FIFO: pos/V register loads are issued BEFORE the next-chunk
// K-DMA, so waiting on them leaves the prefetch in flight; the barrier that drains
// the prefetch arrives a full chunk later. pos tile now feeds MFMAs from registers
// (Pt eliminated); S-phase runs first so pos-load latency hides under it.
__global__ __launch_bounds__(256, 2) void attn3(
    const unsigned short* __restrict__ qb, const unsigned short* __restrict__ kglob,
    const _Float16* __restrict__ vT, const unsigned short* __restrict__ posT,
    unsigned short* __restrict__ ctx) {
  __shared__ unsigned short Kt[2][12288];       // K tile dbuf: 192 rows x 64 d (swizzled)
  __shared__ unsigned short Psh[4 * 16 * PR2];  // P / pos-skew rows (wave-private)

  const int tid = threadIdx.x;
  const int wave = tid >> 6, lane = tid & 63;
  const int q = lane >> 4, l16 = lane & 15;
  const int n = blockIdx.y;
  const int m0 = blockIdx.x * 64;
  const int m0w = m0 + wave * 16;
  const int dsub = lane >> 3;
  const int dswz = (lane & 7) ^ dsub;

  unsigned short* row = Psh + (wave * 16 + l16) * PR2;

  // Q fragments (B-operand): col m = l16, k = q*8+j over d
  const unsigned short* qbase = qb + ((size_t)n * Mq + m0w + l16) * Dq;
  const bf16x8 qf0 = *(const bf16x8*)(qbase + q * 8);
  const bf16x8 qf1 = *(const bf16x8*)(qbase + 32 + q * 8);

  const unsigned short* kbn = kglob + (size_t)n * MKq * Dq;
  const _Float16* vbn = vT + (size_t)n * Dq * MKq;

  f32x4 O[4] = {};
  float zrow = 0.f, mrow = -1e30f;

  // prologue: stage chunk 0 K tile into buffer 0
#pragma unroll
  for (int i = 0; i < 6; i++) {
    const int s = wave + 4 * i;
    const int r = s * 8 + dsub;      // 0..191
    async_ld16(kbn + (size_t)(m0 + r) * Dq + dswz * 8, &Kt[0][s * 512]);
  }

  for (int c = 0; c < 8; c++) {
    const int sbase = c * 128;
    const int j00 = m0w + sbase;     // wave's base

    // drains this chunk's K-DMA (issued a full chunk ago; vmcnt(0) before s_barrier)
    __syncthreads();

    // --- pos fragments -> registers (oldest in FIFO; needed first)
    bf16x8 pf0[8], pf1[8];
#pragma unroll
    for (int t = 0; t < 8; t++) {
      const unsigned short* pp = posT + (size_t)(sbase + t * 16 + l16) * Dq + q * 8;
      pf0[t] = *(const bf16x8*)(pp);
      pf1[t] = *(const bf16x8*)(pp + 32);
    }
    // --- V fragments -> registers (needed last in this chunk)
    f16x8 Vv[5][4];
#pragma unroll
    for (int kt = 0; kt < 5; kt++) {
      int j = j00 + kt * 32 + q * 8;
      if (j > MKq - 8) j = MKq - 8;  // clamped cols have P==0
#pragma unroll
      for (int dt = 0; dt < 4; dt++)
        Vv[kt][dt] = *(const f16x8*)(vbn + (size_t)(dt * 16 + l16) * MKq + j);
    }
    // pin issue order: reg loads above must precede the prefetch DMA below,
    // so their vmcnt waits leave the prefetch outstanding.
    __builtin_amdgcn_sched_barrier(0);

    // --- prefetch chunk c+1's K tile into the other buffer
    if (c < 7) {
      const int jb = m0 + sbase + 128;
      unsigned short* kd = Kt[(c + 1) & 1];
#pragma unroll
      for (int i = 0; i < 6; i++) {
        const int s = wave + 4 * i;
        const int r = s * 8 + dsub;
        async_ld16(kbn + (size_t)(jb + r) * Dq + dswz * 8, kd + s * 512);
      }
    }

    const unsigned short* Kc = Kt[c & 1];

    // --- ctx logits S^T[j][m] from K tile (LDS only; no vmem wait here)
    f32x4 S[9];
#pragma unroll
    for (int t = 0; t < 9; t++) {
      const int rl = wave * 16 + t * 16 + l16;  // 0..191
      const int ch = (q ^ (l16 & 7)) * 8;
      const bf16x8 k0 = *(const bf16x8*)(Kc + rl * 64 + ch);
      const bf16x8 k1 = *(const bf16x8*)(Kc + rl * 64 + (ch ^ 32));
      f32x4 a = {};
      a = mfma_bf16(k0, qf0, a);
      a = mfma_bf16(k1, qf1, a);
      S[t] = a;
    }

    // --- pos logits from registers -> skewed rows: col = 16 + s_local + m
#pragma unroll
    for (int t = 0; t < 8; t++) {
      f32x4 b = {};
      b = mfma_bf16(pf0[t], qf0, b);
      b = mfma_bf16(pf1[t], qf1, b);
      const int cw = 16 + t * 16 + 4 * q + l16;
      row[cw + 0] = f2bf(b[0]);
      row[cw + 1] = f2bf(b[1]);
      row[cw + 2] = f2bf(b[2]);
      row[cw + 3] = f2bf(b[3]);
    }

    // --- skewed pos readback + add + band masks (garbage cols masked below)
#pragma unroll
    for (int t = 0; t < 9; t++) {
      const uint2v pv = *(const uint2v*)(row + 16 + t * 16 + 4 * q);
      S[t][0] += __uint_as_float(pv.x << 16);
      S[t][1] += __uint_as_float(pv.x & 0xffff0000u);
      S[t][2] += __uint_as_float(pv.y << 16);
      S[t][3] += __uint_as_float(pv.y & 0xffff0000u);
    }
#pragma unroll
    for (int r = 0; r < 4; r++) {
      if (4 * q + r < l16) S[0][r] = -1e30f;
      if (4 * q + r >= l16) S[8][r] = -1e30f;
    }

    // --- online softmax in registers
    float mx = -1e30f;
#pragma unroll
    for (int t = 0; t < 9; t++)
      mx = fmaxf(mx, fmaxf(fmaxf(S[t][0], S[t][1]), fmaxf(S[t][2], S[t][3])));
    mx = fmaxf(mx, __shfl_xor(mx, 16, 64));
    mx = fmaxf(mx, __shfl_xor(mx, 32, 64));
    const float m_new = fmaxf(mrow, mx);
    const float alpha = __expf((mrow - m_new) * 0.125f);
    float zs = 0.f;
#pragma unroll
    for (int t = 0; t < 9; t++) {
#pragma unroll
      for (int r = 0; r < 4; r++) {
        const float e = __expf((S[t][r] - m_new) * 0.125f);
        S[t][r] = e; zs += e;
      }
    }
    zs += __shfl_xor(zs, 16, 64);
    zs += __shfl_xor(zs, 32, 64);
    zrow = zrow * alpha + zs;
    mrow = m_new;
#pragma unroll
    for (int dt = 0; dt < 4; dt++) O[dt] *= alpha;

    // --- P -> LDS f16 at [m][j_local]; zero tail [144,160)
#pragma unroll
    for (int t = 0; t < 9; t++) {
      *(unsigned*)(row + t * 16 + 4 * q) = pk_f16(S[t][0], S[t][1]);
      *(unsigned*)(row + t * 16 + 4 * q + 2) = pk_f16(S[t][2], S[t][3]);
    }
    *(unsigned*)(row + 144 + 4 * q) = 0u;
    *(unsigned*)(row + 144 + 4 * q + 2) = 0u;

    // --- PV: O^T += V^T . P^T  (V wait leaves the K prefetch in flight)
    f16x8 Bf[5];
#pragma unroll
    for (int kt = 0; kt < 5; kt++)
      Bf[kt] = *(const f16x8*)(row + kt * 32 + q * 8);
#pragma unroll
    for (int kt = 0; kt < 5; kt++)
#pragma unroll
      for (int dt = 0; dt < 4; dt++)
        O[dt] = mfma_f16(Vv[kt][dt], Bf[kt], O[dt]);
  }

  // epilogue: ctx[b*M + m][head*64 + d] = O/Z  (lane owns row m = l16)
  const float zi = 1.f / zrow;
  unsigned short* cp = ctx + ((size_t)(n >> 3) * Mq + m0w + l16) * Hq + (n & 7) * Dq;
#pragma unroll
  for (int dt = 0; dt < 4; dt++)
#pragma unroll
    for (int r = 0; r < 4; r++)
      cp[dt * 16 + q * 4 + r] = f2bf(O[dt][r] * zi);
}

extern "C" void kernel_launch(void* const* d_in, const int* in_sizes, int n_in,
                              void* d_out, int out_size, void* d_ws, size_t ws_size,
                              hipStream_t stream) {
  const float* query = (const float*)d_in[0];
  const float* key   = (const float*)d_in[1];
  const float* value = (const float*)d_in[2];
  const float* pos   = (const float*)d_in[3];
  const float* Wq    = (const float*)d_in[4];
  const float* Wk    = (const float*)d_in[5];
  const float* Wv    = (const float*)d_in[6];
  const float* Wo    = (const float*)d_in[7];
  float* out = (float*)d_out;

  char* w = (char*)d_ws;
  unsigned short* qb   = (unsigned short*)w; w += (size_t)64 * Mq * Dq * 2;    // 8 MB
  unsigned short* kbuf = (unsigned short*)w; w += (size_t)64 * MKq * Dq * 2;   // 16 MB
  _Float16*       vTb  = (_Float16*)w;       w += (size_t)64 * Dq * MKq * 2;   // 16 MB
  unsigned short* posT = (unsigned short*)w; w += (size_t)SPANq * Dq * 2;      // 128 KB
  unsigned short* WTq  = (unsigned short*)w; w += (size_t)Hq * Hq * 2;
  unsigned short* WTk  = (unsigned short*)w; w += (size_t)Hq * Hq * 2;
  unsigned short* WTv  = (unsigned short*)w; w += (size_t)Hq * Hq * 2;
  unsigned short* WTo  = (unsigned short*)w; w += (size_t)Hq * Hq * 2;
  unsigned short* ctx  = (unsigned short*)w; w += (size_t)Bq * Mq * Hq * 2;    // 8 MB

  prep_transpose<<<272, 256, 0, stream>>>(Wq, Wk, Wv, Wo, pos, WTq, WTk, WTv, WTo, posT);
  gemm_qkv<<<dim3(320, 4), 256, 0, stream>>>(query, key, value, WTq, WTk, WTv, qb, kbuf, vTb);
  attn3<<<dim3(16, 64), 256, 0, stream>>>(qb, kbuf, vTb, posT, ctx);
  gemm128<<<dim3(64, 4), 256, 0, stream>>>(ctx, WTo, nullptr, nullptr, out, 3, 10);
}

// Round 8
// 313.428 us; speedup vs baseline: 1.1029x; 1.1029x over previous
//
#include <hip/hip_runtime.h>
#include <stdint.h>

#define Bq 8
#define Mq 1024
#define Hq 512
#define NHq 8
#define Dq 64
#define SPANq 1024
#define MKq 2048
#define PR2 168   // attn P-row stride (ushorts); 160 used

typedef __bf16 bf16x8 __attribute__((ext_vector_type(8)));
typedef _Float16 f16x8 __attribute__((ext_vector_type(8)));
typedef float f32x4 __attribute__((ext_vector_type(4)));
typedef unsigned short ushort8 __attribute__((ext_vector_type(8)));
typedef unsigned int uint2v __attribute__((ext_vector_type(2)));
typedef unsigned int uint4v __attribute__((ext_vector_type(4)));

static __device__ __forceinline__ unsigned short f2bf(float f) {
  union { float f; unsigned u; } x; x.f = f;
  unsigned r = x.u + 0x7FFFu + ((x.u >> 16) & 1u);
  return (unsigned short)(r >> 16);
}

static __device__ __forceinline__ unsigned pk_f16(float a, float b) {
  return __builtin_bit_cast(unsigned, __builtin_amdgcn_cvt_pkrtz(a, b));
}

// packed f32x2 -> bf16x2 (RNE), gfx940+ instruction (no builtin)
static __device__ __forceinline__ unsigned pk_bf16(float a, float b) {
  unsigned r;
  asm("v_cvt_pk_bf16_f32 %0, %1, %2" : "=v"(r) : "v"(a), "v"(b));
  return r;
}

static __device__ __forceinline__ f32x4 mfma_bf16(bf16x8 a, bf16x8 b, f32x4 c) {
  return __builtin_amdgcn_mfma_f32_16x16x32_bf16(a, b, c, 0, 0, 0);
}
static __device__ __forceinline__ f32x4 mfma_f16(f16x8 a, f16x8 b, f32x4 c) {
  return __builtin_amdgcn_mfma_f32_16x16x32_f16(a, b, c, 0, 0, 0);
}

// async 16B/lane global->LDS DMA; lds dest = uniform base + lane*16
static __device__ __forceinline__ void async_ld16(const void* g, void* l) {
  __builtin_amdgcn_global_load_lds(
      (const __attribute__((address_space(1))) void*)g,
      (__attribute__((address_space(3))) void*)l, 16, 0, 0);
}

// ---------------- prep: transpose+convert weights (WT[o][i]=W[i][o]) and pos (posT[s][d]=pos[d][s])
__global__ __launch_bounds__(256) void prep_transpose(
    const float* __restrict__ Wq, const float* __restrict__ Wk,
    const float* __restrict__ Wv, const float* __restrict__ Wo,
    const float* __restrict__ pos,
    unsigned short* __restrict__ WTq, unsigned short* __restrict__ WTk,
    unsigned short* __restrict__ WTv, unsigned short* __restrict__ WTo,
    unsigned short* __restrict__ posT) {
  __shared__ float tile[64][65];
  const int bid = blockIdx.x;
  const float* src; unsigned short* dst;
  int src_stride, dst_stride, i0, o0;
  if (bid < 256) {
    const int w = bid >> 6, t = bid & 63;
    src = (w == 0) ? Wq : (w == 1) ? Wk : (w == 2) ? Wv : Wo;
    dst = (w == 0) ? WTq : (w == 1) ? WTk : (w == 2) ? WTv : WTo;
    src_stride = Hq; dst_stride = Hq;
    i0 = (t >> 3) * 64; o0 = (t & 7) * 64;
  } else {
    const int t = bid - 256;
    src = pos; dst = posT;
    src_stride = SPANq; dst_stride = Dq;
    i0 = 0; o0 = t * 64;
  }
  const int tid = threadIdx.x;
  for (int e = tid; e < 4096; e += 256) {
    const int r = e >> 6, c = e & 63;
    tile[r][c] = src[(size_t)(i0 + r) * src_stride + o0 + c];
  }
  __syncthreads();
  for (int e = tid; e < 4096; e += 256) {
    const int r = e >> 6, c = e & 63;
    dst[(size_t)(o0 + r) * dst_stride + i0 + c] = f2bf(tile[c][r]);
  }
}

// ---------------- 128x128 GEMM via global_load_lds staging (BK=64, XOR-swizzled)
// bf16 A input (used for out-projection, mode 3: fp32 row-major output)
__global__ __launch_bounds__(256, 2) void gemm128(
    const unsigned short* __restrict__ Xb, const unsigned short* __restrict__ WT,
    unsigned short* __restrict__ outb, _Float16* __restrict__ outv,
    float* __restrict__ outf, int mode, int tshift) {
  __shared__ unsigned short sh[18432];   // 36 KB
  unsigned short* As = sh;               // [128][64] unpadded, swizzled
  unsigned short* Bs = sh + 8192;
  const int tid = threadIdx.x;
  const int wave = tid >> 6, lane = tid & 63;
  const int q = lane >> 4, l16 = lane & 15;
  const int wy = wave >> 1, wx = wave & 1;
  const size_t m0 = (size_t)blockIdx.x * 128;
  const int n0 = blockIdx.y * 128;
  const int dsub = lane >> 3;                 // row offset within slot
  const int dswz = (lane & 7) ^ dsub;         // swizzled source chunk

  f32x4 acc[4][4] = {};

  for (int k0 = 0; k0 < Hq; k0 += 64) {
    __syncthreads();
#pragma unroll
    for (int i = 0; i < 4; i++) {
      const int s = wave * 4 + i;             // slot 0..15, 8 rows each
      const int r = s * 8 + dsub;             // row 0..127
      async_ld16(Xb + (m0 + r) * Hq + k0 + dswz * 8, As + s * 512);
      async_ld16(WT + (size_t)(n0 + r) * Hq + k0 + dswz * 8, Bs + s * 512);
    }
    __syncthreads();
    bf16x8 af[2][4], bg[2][4];
#pragma unroll
    for (int h = 0; h < 2; h++) {
#pragma unroll
      for (int mt = 0; mt < 4; mt++) {
        const int R = wy * 64 + mt * 16 + l16;
        af[h][mt] = *(const bf16x8*)(As + R * 64 + (((h * 4 + q) ^ (l16 & 7)) * 8));
      }
#pragma unroll
      for (int nt = 0; nt < 4; nt++) {
        const int R = wx * 64 + nt * 16 + l16;
        bg[h][nt] = *(const bf16x8*)(Bs + R * 64 + (((h * 4 + q) ^ (l16 & 7)) * 8));
      }
    }
#pragma unroll
    for (int h = 0; h < 2; h++)
#pragma unroll
      for (int mt = 0; mt < 4; mt++)
#pragma unroll
        for (int nt = 0; nt < 4; nt++)
          acc[mt][nt] = mfma_bf16(af[h][mt], bg[h][nt], acc[mt][nt]);
  }

  const int Tlen = 1 << tshift;
#pragma unroll
  for (int mt = 0; mt < 4; mt++) {
#pragma unroll
    for (int nt = 0; nt < 4; nt++) {
      const int c = n0 + wx * 64 + nt * 16 + l16;
#pragma unroll
      for (int r = 0; r < 4; r++) {
        const int m = (int)m0 + wy * 64 + mt * 16 + q * 4 + r;
        const float val = acc[mt][nt][r];
        if (mode == 3) {
          outf[(size_t)m * Hq + c] = val;
        } else {
          const int b = m >> tshift, t = m & (Tlen - 1);
          const int head = c >> 6, d = c & 63;
          outb[(((size_t)(b * 8 + head) << tshift) + t) * 64 + d] = f2bf(val);
        }
      }
    }
  }
}

// ---------------- fused Q/K/V projection: fp32 X staged directly
__global__ __launch_bounds__(256, 2) void gemm_qkv(
    const float* __restrict__ qF, const float* __restrict__ kF,
    const float* __restrict__ vF,
    const unsigned short* __restrict__ WTq, const unsigned short* __restrict__ WTk,
    const unsigned short* __restrict__ WTv,
    unsigned short* __restrict__ qb, unsigned short* __restrict__ kbuf,
    _Float16* __restrict__ vTb) {
  __shared__ float shf[12288];                 // 48 KB: As fp32 32 KB + Bs bf16 16 KB
  float* As = shf;                             // [128][64] fp32, swizzled
  unsigned short* Bs = (unsigned short*)(shf + 8192);

  const int x = blockIdx.x;
  const float* Xf; const unsigned short* WT;
  unsigned short* outb = nullptr; _Float16* outv = nullptr;
  int mode, tshift, bx;
  if (x < 64)       { Xf = qF; WT = WTq; outb = qb;   mode = 0; tshift = 10; bx = x; }
  else if (x < 192) { Xf = kF; WT = WTk; outb = kbuf; mode = 0; tshift = 11; bx = x - 64; }
  else              { Xf = vF; WT = WTv; outv = vTb;  mode = 2; tshift = 11; bx = x - 192; }

  const int tid = threadIdx.x;
  const int wave = tid >> 6, lane = tid & 63;
  const int q = lane >> 4, l16 = lane & 15;
  const int wy = wave >> 1, wx = wave & 1;
  const size_t m0 = (size_t)bx * 128;
  const int n0 = blockIdx.y * 128;
  const int dsub = lane >> 3;
  const int dswz = (lane & 7) ^ dsub;
  const int arow = lane >> 4;                  // 0..3 within A slot
  const int apos = lane & 15;                  // chunk position 0..15

  f32x4 acc[4][4] = {};

  for (int k0 = 0; k0 < Hq; k0 += 64) {
    __syncthreads();
#pragma unroll
    for (int i = 0; i < 8; i++) {
      const int s = wave * 8 + i;              // A slot 0..31, 4 rows each
      const int r = s * 4 + arow;              // row 0..127
      const int gsw = apos ^ (((s & 1) << 2) | arow);  // = apos ^ (r&7)
      async_ld16(Xf + (m0 + r) * Hq + k0 + gsw * 4, As + s * 256);
    }
#pragma unroll
    for (int i = 0; i < 4; i++) {
      const int s = wave * 4 + i;              // B slot 0..15, 8 rows each
      const int r = s * 8 + dsub;
      async_ld16(WT + (size_t)(n0 + r) * Hq + k0 + dswz * 8, Bs + s * 512);
    }
    __syncthreads();

    bf16x8 af[2][4], bg[2][4];
#pragma unroll
    for (int h = 0; h < 2; h++) {
#pragma unroll
      for (int mt = 0; mt < 4; mt++) {
        const int R = wy * 64 + mt * 16 + l16;
        const int xr = R & 7;
        const int c0 = h * 8 + q * 2;          // 4-float chunk index (k = c0*4)
        const f32x4 a0 = *(const f32x4*)(As + R * 64 + ((c0 ^ xr) * 4));
        const f32x4 a1 = *(const f32x4*)(As + R * 64 + (((c0 + 1) ^ xr) * 4));
        uint4v w;
        w[0] = pk_bf16(a0[0], a0[1]);
        w[1] = pk_bf16(a0[2], a0[3]);
        w[2] = pk_bf16(a1[0], a1[1]);
        w[3] = pk_bf16(a1[2], a1[3]);
        af[h][mt] = __builtin_bit_cast(bf16x8, w);
      }
#pragma unroll
      for (int nt = 0; nt < 4; nt++) {
        const int R = wx * 64 + nt * 16 + l16;
        bg[h][nt] = *(const bf16x8*)(Bs + R * 64 + (((h * 4 + q) ^ (l16 & 7)) * 8));
      }
    }
#pragma unroll
    for (int h = 0; h < 2; h++)
#pragma unroll
      for (int mt = 0; mt < 4; mt++)
#pragma unroll
        for (int nt = 0; nt < 4; nt++)
          acc[mt][nt] = mfma_bf16(af[h][mt], bg[h][nt], acc[mt][nt]);
  }

  if (mode == 2) {
    __syncthreads();  // protect tile LDS before reuse
    _Float16* tr = (_Float16*)shf + wave * 4608;  // [64][72]
#pragma unroll
    for (int nt = 0; nt < 4; nt++)
#pragma unroll
      for (int mt = 0; mt < 4; mt++)
#pragma unroll
        for (int r = 0; r < 4; r++)
          tr[(nt * 16 + l16) * 72 + mt * 16 + q * 4 + r] = (_Float16)acc[mt][nt][r];
    const int head = blockIdx.y * 2 + wx;
    const int mrow0 = (int)m0 + wy * 64;
    const int Tlen = 1 << tshift;
    const int b = mrow0 >> tshift, t0 = mrow0 & (Tlen - 1);
#pragma unroll
    for (int it = 0; it < 8; it++) {
      const int dl = it * 8 + (lane >> 3), tl = (lane & 7) * 8;
      const f16x8 v = *(const f16x8*)(tr + dl * 72 + tl);
      *(f16x8*)(outv + ((size_t)((b * 8 + head) * 64 + dl)) * Tlen + t0 + tl) = v;
    }
    return;
  }

  const int Tlen = 1 << tshift;
#pragma unroll
  for (int mt = 0; mt < 4; mt++) {
#pragma unroll
    for (int nt = 0; nt < 4; nt++) {
      const int c = n0 + wx * 64 + nt * 16 + l16;
#pragma unroll
      for (int r = 0; r < 4; r++) {
        const int m = (int)m0 + wy * 64 + mt * 16 + q * 4 + r;
        const int b = m >> tshift, t = m & (Tlen - 1);
        const int head = c >> 6, d = c & 63;
        outb[(((size_t)(b * 8 + head) << tshift) + t) * 64 + d] = f2bf(acc[mt][nt][r]);
      }
    }
  }
}

// ---------------- banded attention: K ring pipeline, one __syncthreads per chunk.
// Ring of 3 x 128-row K sub-tiles: chunk c reads sub-tiles {c, c+1}; sub-tile c+2 is
// DMA'd after the chunk-top barrier into the slot chunk c-1 vacated. The prefetch
// issued at chunk c drains at chunk c+1's barrier -- a full chunk of compute in
// between, so the drain is overlapped. pos comes from registers (issued before the
// prefetch = older in the vmcnt FIFO, dead after pos-phase); V loads stay at r0's
// post-P-write position (live only in PV) -> phase-disjoint register pressure.
__global__ __launch_bounds__(256, 2) void attn3(
    const unsigned short* __restrict__ qb, const unsigned short* __restrict__ kglob,
    const _Float16* __restrict__ vT, const unsigned short* __restrict__ posT,
    unsigned short* __restrict__ ctx) {
  __shared__ unsigned short Kr[3 * 8192];       // 3 sub-tiles x 128 rows x 64 d, 48 KB
  __shared__ unsigned short Psh[4 * 16 * PR2];  // P / pos-skew rows (wave-private), 21 KB

  const int tid = threadIdx.x;
  const int wave = tid >> 6, lane = tid & 63;
  const int q = lane >> 4, l16 = lane & 15;
  const int n = blockIdx.y;
  const int m0 = blockIdx.x * 64;
  const int m0w = m0 + wave * 16;
  const int dsub = lane >> 3;
  const int dswz = (lane & 7) ^ dsub;

  unsigned short* row = Psh + (wave * 16 + l16) * PR2;

  // Q fragments (B-operand): col m = l16, k = q*8+j over d
  const unsigned short* qbase = qb + ((size_t)n * Mq + m0w + l16) * Dq;
  const bf16x8 qf0 = *(const bf16x8*)(qbase + q * 8);
  const bf16x8 qf1 = *(const bf16x8*)(qbase + 32 + q * 8);

  const unsigned short* kbn = kglob + (size_t)n * MKq * Dq;
  const _Float16* vbn = vT + (size_t)n * Dq * MKq;

  f32x4 O[4] = {};
  float zrow = 0.f, mrow = -1e30f;

  // prologue: stage K sub-tiles g=0 (slot 0) and g=1 (slot 1)
#pragma unroll
  for (int g = 0; g < 2; g++)
#pragma unroll
    for (int i = 0; i < 4; i++) {
      const int s = wave + 4 * i;              // slot-local 0..15 (8 rows each)
      const int r = g * 128 + s * 8 + dsub;    // 0..255
      async_ld16(kbn + (size_t)(m0 + r) * Dq + dswz * 8, Kr + g * 8192 + s * 512);
    }

  int c0 = 0, c1 = 1;  // c%3, (c+1)%3
  for (int c = 0; c < 8; c++) {
    // single sync point per chunk: drains all outstanding DMA (vmcnt(0) lgkmcnt(0)
    // + s_barrier) and joins all waves past chunk c-1's reads of the slot we refill
    __syncthreads();

    const int sbase = c * 128;
    const int j00 = m0w + sbase;

    // --- pos fragments -> registers (oldest in FIFO; dead after pos-phase)
    bf16x8 pf0[8], pf1[8];
#pragma unroll
    for (int t = 0; t < 8; t++) {
      const unsigned short* pp = posT + (size_t)(sbase + t * 16 + l16) * Dq + q * 8;
      pf0[t] = *(const bf16x8*)(pp);
      pf1[t] = *(const bf16x8*)(pp + 32);
    }

    // --- prefetch K sub-tile g=c+2 into slot (c+2)%3 (chunk c-1's vacated slot)
    if (c < 7) {
      const int slot2 = (c0 + 2 >= 3) ? c0 - 1 : c0 + 2;
#pragma unroll
      for (int i = 0; i < 4; i++) {
        const int s = wave + 4 * i;
        int r = m0 + (c + 2) * 128 + s * 8 + dsub;
        if (r > MKq - 1) r = MKq - 1;  // clamp pad rows (never read by compute)
        async_ld16(kbn + (size_t)r * Dq + dswz * 8, Kr + slot2 * 8192 + s * 512);
      }
    }

    // --- ctx logits S^T[j][m] from the ring (LDS only; no vmem wait)
    f32x4 S[9];
#pragma unroll
    for (int t = 0; t < 9; t++) {
      const int rl = wave * 16 + t * 16 + l16;  // 0..191
      const int hi = (wave + t) >> 3;           // rl >= 128
      const int slot = hi ? c1 : c0;
      const int ch = (q ^ (l16 & 7)) * 8;
      const unsigned short* Kp = Kr + slot * 8192 + (rl & 127) * 64;
      const bf16x8 k0 = *(const bf16x8*)(Kp + ch);
      const bf16x8 k1 = *(const bf16x8*)(Kp + (ch ^ 32));
      f32x4 a = {};
      a = mfma_bf16(k0, qf0, a);
      a = mfma_bf16(k1, qf1, a);
      S[t] = a;
    }

    // --- pos logits from registers -> skewed rows: col = 16 + s_local + m
#pragma unroll
    for (int t = 0; t < 8; t++) {
      f32x4 b = {};
      b = mfma_bf16(pf0[t], qf0, b);
      b = mfma_bf16(pf1[t], qf1, b);
      const int cw = 16 + t * 16 + 4 * q + l16;
      row[cw + 0] = f2bf(b[0]);
      row[cw + 1] = f2bf(b[1]);
      row[cw + 2] = f2bf(b[2]);
      row[cw + 3] = f2bf(b[3]);
    }

    // --- skewed pos readback + add + band masks (garbage cols masked below)
#pragma unroll
    for (int t = 0; t < 9; t++) {
      const uint2v pv = *(const uint2v*)(row + 16 + t * 16 + 4 * q);
      S[t][0] += __uint_as_float(pv.x << 16);
      S[t][1] += __uint_as_float(pv.x & 0xffff0000u);
      S[t][2] += __uint_as_float(pv.y << 16);
      S[t][3] += __uint_as_float(pv.y & 0xffff0000u);
    }
#pragma unroll
    for (int r = 0; r < 4; r++) {
      if (4 * q + r < l16) S[0][r] = -1e30f;
      if (4 * q + r >= l16) S[8][r] = -1e30f;
    }

    // --- online softmax in registers
    float mx = -1e30f;
#pragma unroll
    for (int t = 0; t < 9; t++)
      mx = fmaxf(mx, fmaxf(fmaxf(S[t][0], S[t][1]), fmaxf(S[t][2], S[t][3])));
    mx = fmaxf(mx, __shfl_xor(mx, 16, 64));
    mx = fmaxf(mx, __shfl_xor(mx, 32, 64));
    const float m_new = fmaxf(mrow, mx);
    const float alpha = __expf((mrow - m_new) * 0.125f);
    float zs = 0.f;
#pragma unroll
    for (int t = 0; t < 9; t++) {
#pragma unroll
      for (int r = 0; r < 4; r++) {
        const float e = __expf((S[t][r] - m_new) * 0.125f);
        S[t][r] = e; zs += e;
      }
    }
    zs += __shfl_xor(zs, 16, 64);
    zs += __shfl_xor(zs, 32, 64);
    zrow = zrow * alpha + zs;
    mrow = m_new;
#pragma unroll
    for (int dt = 0; dt < 4; dt++) O[dt] *= alpha;

    // --- P -> LDS f16 at [m][j_local]; zero tail [144,160)
#pragma unroll
    for (int t = 0; t < 9; t++) {
      *(unsigned*)(row + t * 16 + 4 * q) = pk_f16(S[t][0], S[t][1]);
      *(unsigned*)(row + t * 16 + 4 * q + 2) = pk_f16(S[t][2], S[t][3]);
    }
    *(unsigned*)(row + 144 + 4 * q) = 0u;
    *(unsigned*)(row + 144 + 4 * q + 2) = 0u;

    // --- PV: O^T += V^T . P^T  (V direct from global, r0 position)
    f16x8 Bf[5];
#pragma unroll
    for (int kt = 0; kt < 5; kt++)
      Bf[kt] = *(const f16x8*)(row + kt * 32 + q * 8);
    f16x8 Vv[5][4];
#pragma unroll
    for (int kt = 0; kt < 5; kt++) {
      int j = j00 + kt * 32 + q * 8;
      if (j > MKq - 8) j = MKq - 8;  // clamped cols have P==0
#pragma unroll
      for (int dt = 0; dt < 4; dt++)
        Vv[kt][dt] = *(const f16x8*)(vbn + (size_t)(dt * 16 + l16) * MKq + j);
    }
#pragma unroll
    for (int kt = 0; kt < 5; kt++)
#pragma unroll
      for (int dt = 0; dt < 4; dt++)
        O[dt] = mfma_f16(Vv[kt][dt], Bf[kt], O[dt]);

    // rotate ring indices
    const int nc1 = (c1 + 1 >= 3) ? 0 : c1 + 1;
    c0 = c1; c1 = nc1;
  }

  // epilogue: ctx[b*M + m][head*64 + d] = O/Z  (lane owns row m = l16)
  const float zi = 1.f / zrow;
  unsigned short* cp = ctx + ((size_t)(n >> 3) * Mq + m0w + l16) * Hq + (n & 7) * Dq;
#pragma unroll
  for (int dt = 0; dt < 4; dt++)
#pragma unroll
    for (int r = 0; r < 4; r++)
      cp[dt * 16 + q * 4 + r] = f2bf(O[dt][r] * zi);
}

extern "C" void kernel_launch(void* const* d_in, const int* in_sizes, int n_in,
                              void* d_out, int out_size, void* d_ws, size_t ws_size,
                              hipStream_t stream) {
  const float* query = (const float*)d_in[0];
  const float* key   = (const float*)d_in[1];
  const float* value = (const float*)d_in[2];
  const float* pos   = (const float*)d_in[3];
  const float* Wq    = (const float*)d_in[4];
  const float* Wk    = (const float*)d_in[5];
  const float* Wv    = (const float*)d_in[6];
  const float* Wo    = (const float*)d_in[7];
  float* out = (float*)d_out;

  char* w = (char*)d_ws;
  unsigned short* qb   = (unsigned short*)w; w += (size_t)64 * Mq * Dq * 2;    // 8 MB
  unsigned short* kbuf = (unsigned short*)w; w += (size_t)64 * MKq * Dq * 2;   // 16 MB
  _Float16*       vTb  = (_Float16*)w;       w += (size_t)64 * Dq * MKq * 2;   // 16 MB
  unsigned short* posT = (unsigned short*)w; w += (size_t)SPANq * Dq * 2;      // 128 KB
  unsigned short* WTq  = (unsigned short*)w; w += (size_t)Hq * Hq * 2;
  unsigned short* WTk  = (unsigned short*)w; w += (size_t)Hq * Hq * 2;
  unsigned short* WTv  = (unsigned short*)w; w += (size_t)Hq * Hq * 2;
  unsigned short* WTo  = (unsigned short*)w; w += (size_t)Hq * Hq * 2;
  unsigned short* ctx  = (unsigned short*)w; w += (size_t)Bq * Mq * Hq * 2;    // 8 MB

  prep_transpose<<<272, 256, 0, stream>>>(Wq, Wk, Wv, Wo, pos, WTq, WTk, WTv, WTo, posT);
  gemm_qkv<<<dim3(320, 4), 256, 0, stream>>>(query, key, value, WTq, WTk, WTv, qb, kbuf, vTb);
  attn3<<<dim3(16, 64), 256, 0, stream>>>(qb, kbuf, vTb, posT, ctx);
  gemm128<<<dim3(64, 4), 256, 0, stream>>>(ctx, WTo, nullptr, nullptr, out, 3, 10);
}

// Round 9
// 265.320 us; speedup vs baseline: 1.3028x; 1.1813x over previous
//
#include <hip/hip_runtime.h>
#include <stdint.h>

#define Bq 8
#define Mq 1024
#define Hq 512
#define NHq 8
#define Dq 64
#define SPANq 1024
#define MKq 2048
#define PR2 168   // attn P-row stride (ushorts); 160 used

typedef __bf16 bf16x8 __attribute__((ext_vector_type(8)));
typedef _Float16 f16x8 __attribute__((ext_vector_type(8)));
typedef float f32x4 __attribute__((ext_vector_type(4)));
typedef unsigned short ushort8 __attribute__((ext_vector_type(8)));
typedef unsigned int uint2v __attribute__((ext_vector_type(2)));
typedef unsigned int uint4v __attribute__((ext_vector_type(4)));

static __device__ __forceinline__ unsigned short f2bf(float f) {
  union { float f; unsigned u; } x; x.f = f;
  unsigned r = x.u + 0x7FFFu + ((x.u >> 16) & 1u);
  return (unsigned short)(r >> 16);
}

static __device__ __forceinline__ unsigned pk_f16(float a, float b) {
  return __builtin_bit_cast(unsigned, __builtin_amdgcn_cvt_pkrtz(a, b));
}

// packed f32x2 -> bf16x2 (RNE), gfx940+ instruction (no builtin)
static __device__ __forceinline__ unsigned pk_bf16(float a, float b) {
  unsigned r;
  asm("v_cvt_pk_bf16_f32 %0, %1, %2" : "=v"(r) : "v"(a), "v"(b));
  return r;
}

static __device__ __forceinline__ f32x4 mfma_bf16(bf16x8 a, bf16x8 b, f32x4 c) {
  return __builtin_amdgcn_mfma_f32_16x16x32_bf16(a, b, c, 0, 0, 0);
}
static __device__ __forceinline__ f32x4 mfma_f16(f16x8 a, f16x8 b, f32x4 c) {
  return __builtin_amdgcn_mfma_f32_16x16x32_f16(a, b, c, 0, 0, 0);
}

// async 16B/lane global->LDS DMA; lds dest = uniform base + lane*16
static __device__ __forceinline__ void async_ld16(const void* g, void* l) {
  __builtin_amdgcn_global_load_lds(
      (const __attribute__((address_space(1))) void*)g,
      (__attribute__((address_space(3))) void*)l, 16, 0, 0);
}

// ---------------- prep: transpose+convert weights (WT[o][i]=W[i][o]) and pos (posT[s][d]=pos[d][s])
__global__ __launch_bounds__(256) void prep_transpose(
    const float* __restrict__ Wq, const float* __restrict__ Wk,
    const float* __restrict__ Wv, const float* __restrict__ Wo,
    const float* __restrict__ pos,
    unsigned short* __restrict__ WTq, unsigned short* __restrict__ WTk,
    unsigned short* __restrict__ WTv, unsigned short* __restrict__ WTo,
    unsigned short* __restrict__ posT) {
  __shared__ float tile[64][65];
  const int bid = blockIdx.x;
  const float* src; unsigned short* dst;
  int src_stride, dst_stride, i0, o0;
  if (bid < 256) {
    const int w = bid >> 6, t = bid & 63;
    src = (w == 0) ? Wq : (w == 1) ? Wk : (w == 2) ? Wv : Wo;
    dst = (w == 0) ? WTq : (w == 1) ? WTk : (w == 2) ? WTv : WTo;
    src_stride = Hq; dst_stride = Hq;
    i0 = (t >> 3) * 64; o0 = (t & 7) * 64;
  } else {
    const int t = bid - 256;
    src = pos; dst = posT;
    src_stride = SPANq; dst_stride = Dq;
    i0 = 0; o0 = t * 64;
  }
  const int tid = threadIdx.x;
  for (int e = tid; e < 4096; e += 256) {
    const int r = e >> 6, c = e & 63;
    tile[r][c] = src[(size_t)(i0 + r) * src_stride + o0 + c];
  }
  __syncthreads();
  for (int e = tid; e < 4096; e += 256) {
    const int r = e >> 6, c = e & 63;
    dst[(size_t)(o0 + r) * dst_stride + i0 + c] = f2bf(tile[c][r]);
  }
}

// ---------------- out-projection 128x128 GEMM (bf16 A), 1-D grid with XCD-grouped
// decode: the 4 column-tiles (y) of one A-panel (x) are spaced 8 apart -> same XCD,
// temporally adjacent -> A-panel re-reads hit L2.
__global__ __launch_bounds__(256, 2) void gemm128(
    const unsigned short* __restrict__ Xb, const unsigned short* __restrict__ WT,
    float* __restrict__ outf) {
  __shared__ unsigned short sh[18432];   // 36 KB
  unsigned short* As = sh;               // [128][64] unpadded, swizzled
  unsigned short* Bs = sh + 8192;
  const int tid = threadIdx.x;
  const int wave = tid >> 6, lane = tid & 63;
  const int q = lane >> 4, l16 = lane & 15;
  const int wy = wave >> 1, wx = wave & 1;
  // decode: h = j + 8*(y + 4*xg); x = xg*8 + j  (64 x-panels, 4 y-tiles)
  const int h = blockIdx.x;
  const int j8 = h & 7, rr = h >> 3;
  const int y = rr & 3, xg = rr >> 2;
  const size_t m0 = (size_t)(xg * 8 + j8) * 128;
  const int n0 = y * 128;
  const int dsub = lane >> 3;                 // row offset within slot
  const int dswz = (lane & 7) ^ dsub;         // swizzled source chunk

  f32x4 acc[4][4] = {};

  for (int k0 = 0; k0 < Hq; k0 += 64) {
    __syncthreads();
#pragma unroll
    for (int i = 0; i < 4; i++) {
      const int s = wave * 4 + i;             // slot 0..15, 8 rows each
      const int r = s * 8 + dsub;             // row 0..127
      async_ld16(Xb + (m0 + r) * Hq + k0 + dswz * 8, As + s * 512);
      async_ld16(WT + (size_t)(n0 + r) * Hq + k0 + dswz * 8, Bs + s * 512);
    }
    __syncthreads();
    bf16x8 af[2][4], bg[2][4];
#pragma unroll
    for (int hh = 0; hh < 2; hh++) {
#pragma unroll
      for (int mt = 0; mt < 4; mt++) {
        const int R = wy * 64 + mt * 16 + l16;
        af[hh][mt] = *(const bf16x8*)(As + R * 64 + (((hh * 4 + q) ^ (l16 & 7)) * 8));
      }
#pragma unroll
      for (int nt = 0; nt < 4; nt++) {
        const int R = wx * 64 + nt * 16 + l16;
        bg[hh][nt] = *(const bf16x8*)(Bs + R * 64 + (((hh * 4 + q) ^ (l16 & 7)) * 8));
      }
    }
#pragma unroll
    for (int hh = 0; hh < 2; hh++)
#pragma unroll
      for (int mt = 0; mt < 4; mt++)
#pragma unroll
        for (int nt = 0; nt < 4; nt++)
          acc[mt][nt] = mfma_bf16(af[hh][mt], bg[hh][nt], acc[mt][nt]);
  }

#pragma unroll
  for (int mt = 0; mt < 4; mt++) {
#pragma unroll
    for (int nt = 0; nt < 4; nt++) {
      const int c = n0 + wx * 64 + nt * 16 + l16;
#pragma unroll
      for (int r = 0; r < 4; r++) {
        const int m = (int)m0 + wy * 64 + mt * 16 + q * 4 + r;
        outf[(size_t)m * Hq + c] = acc[mt][nt][r];
      }
    }
  }
}

// ---------------- fused Q/K/V projection: fp32 X staged directly; 1-D grid with
// XCD-grouped decode (4 y-tiles of one x-panel -> same XCD, adjacent -> L2 reuse).
__global__ __launch_bounds__(256, 2) void gemm_qkv(
    const float* __restrict__ qF, const float* __restrict__ kF,
    const float* __restrict__ vF,
    const unsigned short* __restrict__ WTq, const unsigned short* __restrict__ WTk,
    const unsigned short* __restrict__ WTv,
    unsigned short* __restrict__ qb, unsigned short* __restrict__ kbuf,
    _Float16* __restrict__ vTb) {
  __shared__ float shf[12288];                 // 48 KB: As fp32 32 KB + Bs bf16 16 KB
  float* As = shf;                             // [128][64] fp32, swizzled
  unsigned short* Bs = (unsigned short*)(shf + 8192);

  // decode: h = j + 8*(y + 4*xg); x = xg*8 + j  (320 x-panels, 4 y-tiles)
  const int h = blockIdx.x;
  const int j8 = h & 7, rr = h >> 3;
  const int y = rr & 3, xg = rr >> 2;
  const int x = xg * 8 + j8;                   // 0..319
  const int n0 = y * 128;

  const float* Xf; const unsigned short* WT;
  unsigned short* outb = nullptr; _Float16* outv = nullptr;
  int mode, tshift, bx;
  if (x < 64)       { Xf = qF; WT = WTq; outb = qb;   mode = 0; tshift = 10; bx = x; }
  else if (x < 192) { Xf = kF; WT = WTk; outb = kbuf; mode = 0; tshift = 11; bx = x - 64; }
  else              { Xf = vF; WT = WTv; outv = vTb;  mode = 2; tshift = 11; bx = x - 192; }

  const int tid = threadIdx.x;
  const int wave = tid >> 6, lane = tid & 63;
  const int q = lane >> 4, l16 = lane & 15;
  const int wy = wave >> 1, wx = wave & 1;
  const size_t m0 = (size_t)bx * 128;
  const int dsub = lane >> 3;
  const int dswz = (lane & 7) ^ dsub;
  const int arow = lane >> 4;                  // 0..3 within A slot
  const int apos = lane & 15;                  // chunk position 0..15

  f32x4 acc[4][4] = {};

  for (int k0 = 0; k0 < Hq; k0 += 64) {
    __syncthreads();
#pragma unroll
    for (int i = 0; i < 8; i++) {
      const int s = wave * 8 + i;              // A slot 0..31, 4 rows each
      const int r = s * 4 + arow;              // row 0..127
      const int gsw = apos ^ (((s & 1) << 2) | arow);  // = apos ^ (r&7)
      async_ld16(Xf + (m0 + r) * Hq + k0 + gsw * 4, As + s * 256);
    }
#pragma unroll
    for (int i = 0; i < 4; i++) {
      const int s = wave * 4 + i;              // B slot 0..15, 8 rows each
      const int r = s * 8 + dsub;
      async_ld16(WT + (size_t)(n0 + r) * Hq + k0 + dswz * 8, Bs + s * 512);
    }
    __syncthreads();

    bf16x8 af[2][4], bg[2][4];
#pragma unroll
    for (int hh = 0; hh < 2; hh++) {
#pragma unroll
      for (int mt = 0; mt < 4; mt++) {
        const int R = wy * 64 + mt * 16 + l16;
        const int xr = R & 7;
        const int c0 = hh * 8 + q * 2;         // 4-float chunk index (k = c0*4)
        const f32x4 a0 = *(const f32x4*)(As + R * 64 + ((c0 ^ xr) * 4));
        const f32x4 a1 = *(const f32x4*)(As + R * 64 + (((c0 + 1) ^ xr) * 4));
        uint4v w;
        w[0] = pk_bf16(a0[0], a0[1]);
        w[1] = pk_bf16(a0[2], a0[3]);
        w[2] = pk_bf16(a1[0], a1[1]);
        w[3] = pk_bf16(a1[2], a1[3]);
        af[hh][mt] = __builtin_bit_cast(bf16x8, w);
      }
#pragma unroll
      for (int nt = 0; nt < 4; nt++) {
        const int R = wx * 64 + nt * 16 + l16;
        bg[hh][nt] = *(const bf16x8*)(Bs + R * 64 + (((hh * 4 + q) ^ (l16 & 7)) * 8));
      }
    }
#pragma unroll
    for (int hh = 0; hh < 2; hh++)
#pragma unroll
      for (int mt = 0; mt < 4; mt++)
#pragma unroll
        for (int nt = 0; nt < 4; nt++)
          acc[mt][nt] = mfma_bf16(af[hh][mt], bg[hh][nt], acc[mt][nt]);
  }

  if (mode == 2) {
    __syncthreads();  // protect tile LDS before reuse
    _Float16* tr = (_Float16*)shf + wave * 4608;  // [64][72]
#pragma unroll
    for (int nt = 0; nt < 4; nt++)
#pragma unroll
      for (int mt = 0; mt < 4; mt++)
#pragma unroll
        for (int r = 0; r < 4; r++)
          tr[(nt * 16 + l16) * 72 + mt * 16 + q * 4 + r] = (_Float16)acc[mt][nt][r];
    const int head = y * 2 + wx;
    const int mrow0 = (int)m0 + wy * 64;
    const int Tlen = 1 << tshift;
    const int b = mrow0 >> tshift, t0 = mrow0 & (Tlen - 1);
#pragma unroll
    for (int it = 0; it < 8; it++) {
      const int dl = it * 8 + (lane >> 3), tl = (lane & 7) * 8;
      const f16x8 v = *(const f16x8*)(tr + dl * 72 + tl);
      *(f16x8*)(outv + ((size_t)((b * 8 + head) * 64 + dl)) * Tlen + t0 + tl) = v;
    }
    return;
  }

  const int Tlen = 1 << tshift;
#pragma unroll
  for (int mt = 0; mt < 4; mt++) {
#pragma unroll
    for (int nt = 0; nt < 4; nt++) {
      const int c = n0 + wx * 64 + nt * 16 + l16;
#pragma unroll
      for (int r = 0; r < 4; r++) {
        const int m = (int)m0 + wy * 64 + mt * 16 + q * 4 + r;
        const int b = m >> tshift, t = m & (Tlen - 1);
        const int head = c >> 6, d = c & 63;
        outb[(((size_t)(b * 8 + head) << tshift) + t) * 64 + d] = f2bf(acc[mt][nt][r]);
      }
    }
  }
}

// ---------------- banded attention: r0's exact two-barrier LDS-staged structure,
// scaled to 8 waves / 128-query blocks. K tile = 256 rows (32 KB), pos tile 16 KB,
// both amortized over 2x the queries -> per-query staged bytes 625 -> 375 B (-40%),
// and half as many blocks re-stage the shared pos tile. Waves/CU unchanged (8: one
// 512-thread block at 90 KB LDS vs two 256-thread blocks at 62.5 KB).
__global__ __launch_bounds__(512, 1) void attn3(
    const unsigned short* __restrict__ qb, const unsigned short* __restrict__ kglob,
    const _Float16* __restrict__ vT, const unsigned short* __restrict__ posT,
    unsigned short* __restrict__ ctx) {
  __shared__ unsigned short Kt[16384];          // K tile: 256 rows x 64 d (swizzled), 32 KB
  __shared__ unsigned short Pt[8192];           // pos tile: 128 rows x 64 d (swizzled), 16 KB
  __shared__ unsigned short Psh[8 * 16 * PR2];  // P / pos-skew rows (wave-private), 42 KB

  const int tid = threadIdx.x;
  const int wave = tid >> 6, lane = tid & 63;   // wave 0..7
  const int q = lane >> 4, l16 = lane & 15;
  const int n = blockIdx.y;
  const int m0 = blockIdx.x * 128;
  const int m0w = m0 + wave * 16;
  const int dsub = lane >> 3;
  const int dswz = (lane & 7) ^ dsub;

  unsigned short* row = Psh + (wave * 16 + l16) * PR2;

  // Q fragments (B-operand): col m = l16, k = q*8+j over d
  const unsigned short* qbase = qb + ((size_t)n * Mq + m0w + l16) * Dq;
  const bf16x8 qf0 = *(const bf16x8*)(qbase + q * 8);
  const bf16x8 qf1 = *(const bf16x8*)(qbase + 32 + q * 8);

  const unsigned short* kbn = kglob + (size_t)n * MKq * Dq;
  const _Float16* vbn = vT + (size_t)n * Dq * MKq;

  f32x4 O[4] = {};
  float zrow = 0.f, mrow = -1e30f;

  for (int c = 0; c < 8; c++) {
    const int sbase = c * 128;
    const int jb = m0 + sbase;       // K tile base row (block-level)
    const int j00 = m0w + sbase;     // wave's base

    __syncthreads();  // previous chunk's tile reads complete
    // --- DMA K tile: 32 slots x 1 KB (4/wave); pos tile: 16 slots (2/wave)
#pragma unroll
    for (int i = 0; i < 4; i++) {
      const int s = wave + 8 * i;
      const int r = s * 8 + dsub;    // 0..255
      async_ld16(kbn + (size_t)(jb + r) * Dq + dswz * 8, Kt + s * 512);
    }
#pragma unroll
    for (int i = 0; i < 2; i++) {
      const int s = wave + 8 * i;
      const int r = s * 8 + dsub;    // 0..127
      async_ld16(posT + (size_t)(sbase + r) * Dq + dswz * 8, Pt + s * 512);
    }
    __syncthreads();  // DMA drained (compiler emits vmcnt(0) before barrier)

    // --- pos logits -> skewed rows: col = 16 + s_local + m
#pragma unroll
    for (int t = 0; t < 8; t++) {
      const int rl = t * 16 + l16;
      const int ch = (q ^ (l16 & 7)) * 8;
      const bf16x8 p0 = *(const bf16x8*)(Pt + rl * 64 + ch);
      const bf16x8 p1 = *(const bf16x8*)(Pt + rl * 64 + (ch ^ 32));
      f32x4 b = {};
      b = mfma_bf16(p0, qf0, b);
      b = mfma_bf16(p1, qf1, b);
      const int cw = 16 + t * 16 + 4 * q + l16;
      row[cw + 0] = f2bf(b[0]);
      row[cw + 1] = f2bf(b[1]);
      row[cw + 2] = f2bf(b[2]);
      row[cw + 3] = f2bf(b[3]);
    }

    // --- ctx logits S^T[j][m] from K tile + skewed pos readback + band masks
    f32x4 S[9];
#pragma unroll
    for (int t = 0; t < 9; t++) {
      const int rl = wave * 16 + t * 16 + l16;  // 0..255
      const int ch = (q ^ (l16 & 7)) * 8;
      const bf16x8 k0 = *(const bf16x8*)(Kt + rl * 64 + ch);
      const bf16x8 k1 = *(const bf16x8*)(Kt + rl * 64 + (ch ^ 32));
      f32x4 a = {};
      a = mfma_bf16(k0, qf0, a);
      a = mfma_bf16(k1, qf1, a);
      const uint2v pv = *(const uint2v*)(row + 16 + t * 16 + 4 * q);
      a[0] += __uint_as_float(pv.x << 16);
      a[1] += __uint_as_float(pv.x & 0xffff0000u);
      a[2] += __uint_as_float(pv.y << 16);
      a[3] += __uint_as_float(pv.y & 0xffff0000u);
      S[t] = a;
    }
#pragma unroll
    for (int r = 0; r < 4; r++) {
      if (4 * q + r < l16) S[0][r] = -1e30f;
      if (4 * q + r >= l16) S[8][r] = -1e30f;
    }

    // --- online softmax in registers
    float mx = -1e30f;
#pragma unroll
    for (int t = 0; t < 9; t++)
      mx = fmaxf(mx, fmaxf(fmaxf(S[t][0], S[t][1]), fmaxf(S[t][2], S[t][3])));
    mx = fmaxf(mx, __shfl_xor(mx, 16, 64));
    mx = fmaxf(mx, __shfl_xor(mx, 32, 64));
    const float m_new = fmaxf(mrow, mx);
    const float alpha = __expf((mrow - m_new) * 0.125f);
    float zs = 0.f;
#pragma unroll
    for (int t = 0; t < 9; t++) {
#pragma unroll
      for (int r = 0; r < 4; r++) {
        const float e = __expf((S[t][r] - m_new) * 0.125f);
        S[t][r] = e; zs += e;
      }
    }
    zs += __shfl_xor(zs, 16, 64);
    zs += __shfl_xor(zs, 32, 64);
    zrow = zrow * alpha + zs;
    mrow = m_new;
#pragma unroll
    for (int dt = 0; dt < 4; dt++) O[dt] *= alpha;

    // --- P -> LDS f16 at [m][j_local]; zero tail [144,160)
#pragma unroll
    for (int t = 0; t < 9; t++) {
      *(unsigned*)(row + t * 16 + 4 * q) = pk_f16(S[t][0], S[t][1]);
      *(unsigned*)(row + t * 16 + 4 * q + 2) = pk_f16(S[t][2], S[t][3]);
    }
    *(unsigned*)(row + 144 + 4 * q) = 0u;
    *(unsigned*)(row + 144 + 4 * q + 2) = 0u;

    // --- PV: O^T += V^T . P^T  (V direct from global; batch all 20 loads)
    f16x8 Bf[5];
#pragma unroll
    for (int kt = 0; kt < 5; kt++)
      Bf[kt] = *(const f16x8*)(row + kt * 32 + q * 8);
    f16x8 Vv[5][4];
#pragma unroll
    for (int kt = 0; kt < 5; kt++) {
      int j = j00 + kt * 32 + q * 8;
      if (j > MKq - 8) j = MKq - 8;  // clamped cols have P==0
#pragma unroll
      for (int dt = 0; dt < 4; dt++)
        Vv[kt][dt] = *(const f16x8*)(vbn + (size_t)(dt * 16 + l16) * MKq + j);
    }
#pragma unroll
    for (int kt = 0; kt < 5; kt++)
#pragma unroll
      for (int dt = 0; dt < 4; dt++)
        O[dt] = mfma_f16(Vv[kt][dt], Bf[kt], O[dt]);
  }

  // epilogue: ctx[b*M + m][head*64 + d] = O/Z  (lane owns row m = l16)
  const float zi = 1.f / zrow;
  unsigned short* cp = ctx + ((size_t)(n >> 3) * Mq + m0w + l16) * Hq + (n & 7) * Dq;
#pragma unroll
  for (int dt = 0; dt < 4; dt++)
#pragma unroll
    for (int r = 0; r < 4; r++)
      cp[dt * 16 + q * 4 + r] = f2bf(O[dt][r] * zi);
}

extern "C" void kernel_launch(void* const* d_in, const int* in_sizes, int n_in,
                              void* d_out, int out_size, void* d_ws, size_t ws_size,
                              hipStream_t stream) {
  const float* query = (const float*)d_in[0];
  const float* key   = (const float*)d_in[1];
  const float* value = (const float*)d_in[2];
  const float* pos   = (const float*)d_in[3];
  const float* Wq    = (const float*)d_in[4];
  const float* Wk    = (const float*)d_in[5];
  const float* Wv    = (const float*)d_in[6];
  const float* Wo    = (const float*)d_in[7];
  float* out = (float*)d_out;

  char* w = (char*)d_ws;
  unsigned short* qb   = (unsigned short*)w; w += (size_t)64 * Mq * Dq * 2;    // 8 MB
  unsigned short* kbuf = (unsigned short*)w; w += (size_t)64 * MKq * Dq * 2;   // 16 MB
  _Float16*       vTb  = (_Float16*)w;       w += (size_t)64 * Dq * MKq * 2;   // 16 MB
  unsigned short* posT = (unsigned short*)w; w += (size_t)SPANq * Dq * 2;      // 128 KB
  unsigned short* WTq  = (unsigned short*)w; w += (size_t)Hq * Hq * 2;
  unsigned short* WTk  = (unsigned short*)w; w += (size_t)Hq * Hq * 2;
  unsigned short* WTv  = (unsigned short*)w; w += (size_t)Hq * Hq * 2;
  unsigned short* WTo  = (unsigned short*)w; w += (size_t)Hq * Hq * 2;
  unsigned short* ctx  = (unsigned short*)w; w += (size_t)Bq * Mq * Hq * 2;    // 8 MB

  prep_transpose<<<272, 256, 0, stream>>>(Wq, Wk, Wv, Wo, pos, WTq, WTk, WTv, WTo, posT);
  gemm_qkv<<<1280, 256, 0, stream>>>(query, key, value, WTq, WTk, WTv, qb, kbuf, vTb);
  attn3<<<dim3(8, 64), 512, 0, stream>>>(qb, kbuf, vTb, posT, ctx);
  gemm128<<<256, 256, 0, stream>>>(ctx, WTo, out);
}